// Round 4
// baseline (456.972 us; speedup 1.0000x reference)
//
#include <hip/hip_runtime.h>
#include <hip/hip_bf16.h>

#define N_ATOMS 16384
#define N_PAIRS 131072

// ws layout (float offsets)
#define OFF_PA    0                       // [P,52] relu(PA), pad cols zeroed
#define OFF_PASEG 6815744                 // [N,50]
#define OFF_AA    7634944                 // [N,100]
#define OFF_U     9273344                 // [N,52]
#define OFF_V     10125312                // [N,52]
#define OFF_S     10977280                // [N,128]
#define OFF_IDX   13074432                // int[P]
#define OFF_OFS   13205504                // int[N+2]
#define OFF_CNT   13221890                // int[N]  (count -> cursor)
// total ~13.24M floats = 53 MB

// ---------------- K0a: histogram of pair_split
__global__ __launch_bounds__(256) void k0_count(const int* __restrict__ split,
                                                int* __restrict__ cnt)
{
    int p = blockIdx.x * 256 + threadIdx.x;
    atomicAdd(&cnt[split[p]], 1);
}

// ---------------- K0b: exclusive prefix sum over 16384 counts (1 block)
__global__ __launch_bounds__(1024) void k_scan(int* __restrict__ cnt,
                                               int* __restrict__ ofs)
{
    __shared__ int part[1024];
    const int t = threadIdx.x;
    const int base = t * 16;
    int v[16];
    int s = 0;
    #pragma unroll
    for (int i = 0; i < 16; ++i) { v[i] = cnt[base + i]; s += v[i]; }
    part[t] = s;
    __syncthreads();
    for (int off = 1; off < 1024; off <<= 1) {
        int x = (t >= off) ? part[t - off] : 0;
        __syncthreads();
        part[t] += x;
        __syncthreads();
    }
    int excl = part[t] - s;   // exclusive prefix of this thread's chunk
    #pragma unroll
    for (int i = 0; i < 16; ++i) {
        int c = v[i];
        ofs[base + i] = excl;
        cnt[base + i] = excl;   // becomes the fill cursor
        excl += c;
    }
    if (t == 1023) ofs[16384] = excl;
}

// ---------------- K0c: scatter pair ids into buckets
__global__ __launch_bounds__(256) void k0_fill(const int* __restrict__ split,
                                               int* __restrict__ cur,
                                               int* __restrict__ idx)
{
    int p = blockIdx.x * 256 + threadIdx.x;
    int pos = atomicAdd(&cur[split[p]], 1);
    idx[pos] = p;
}

// ---------------- K1: AA = relu(X@Waa+b), U = X@Wap[:256], V = X@Wap[256:]
__global__ __launch_bounds__(256, 2) void k1_atom(
    const float* __restrict__ X,
    const float* __restrict__ Waa, const float* __restrict__ baa,
    const float* __restrict__ Wap,
    float* __restrict__ AA, float* __restrict__ U, float* __restrict__ V)
{
    __shared__ __align__(16) float xt[256][36];   // transposed X tile, pad 36
    const int t = threadIdx.x;
    const int a0 = blockIdx.x * 32;
    #pragma unroll
    for (int r = 0; r < 32; ++r) {                // a = r, k = t : coalesced
        xt[t][r] = X[(size_t)(a0 + r) * 256 + t];
    }
    __syncthreads();
    const int c = t;
    if (c < 200) {
        const float* wp; int stride; float bias = 0.f;
        if (c < 100)      { wp = Waa + c;                  stride = 100; bias = baa[c]; }
        else if (c < 150) { wp = Wap + (c - 100);          stride = 50; }
        else              { wp = Wap + 256*50 + (c - 150); stride = 50; }
        float acc[32];
        #pragma unroll
        for (int a = 0; a < 32; ++a) acc[a] = bias;
        #pragma unroll 4
        for (int k = 0; k < 256; ++k) {
            float w = wp[(size_t)k * stride];
            const float4* xr = (const float4*)&xt[k][0];
            #pragma unroll
            for (int a4 = 0; a4 < 8; ++a4) {
                float4 x = xr[a4];
                acc[a4*4+0] = fmaf(x.x, w, acc[a4*4+0]);
                acc[a4*4+1] = fmaf(x.y, w, acc[a4*4+1]);
                acc[a4*4+2] = fmaf(x.z, w, acc[a4*4+2]);
                acc[a4*4+3] = fmaf(x.w, w, acc[a4*4+3]);
            }
        }
        if (c < 100) {
            #pragma unroll
            for (int a = 0; a < 32; ++a)
                AA[(size_t)(a0 + a) * 100 + c] = fmaxf(acc[a], 0.f);
        } else if (c < 150) {
            #pragma unroll
            for (int a = 0; a < 32; ++a)
                U[(size_t)(a0 + a) * 52 + (c - 100)] = acc[a];
        } else {
            #pragma unroll
            for (int a = 0; a < 32; ++a)
                V[(size_t)(a0 + a) * 52 + (c - 150)] = acc[a];
        }
    } else if (c == 200) {        // zero U pad cols 50,51
        #pragma unroll
        for (int a = 0; a < 32; ++a) {
            U[(size_t)(a0 + a) * 52 + 50] = 0.f;
            U[(size_t)(a0 + a) * 52 + 51] = 0.f;
        }
    } else if (c == 201) {        // zero V pad cols 50,51
        #pragma unroll
        for (int a = 0; a < 32; ++a) {
            V[(size_t)(a0 + a) * 52 + 50] = 0.f;
            V[(size_t)(a0 + a) * 52 + 51] = 0.f;
        }
    }
}

// ---------------- K2a: PA = relu(pf@Wpa+b) -> rows [P,52], no atomics
__global__ __launch_bounds__(256, 2) void k2a_pa(
    const float* __restrict__ PF,
    const float* __restrict__ Wpa, const float* __restrict__ bpa,
    float* __restrict__ PAo)
{
    __shared__ __align__(16) float Wc[64][52];
    __shared__ __align__(16) float bc[52];
    const int t = threadIdx.x;
    for (int i = t; i < 64 * 52; i += 256) {
        int k = i / 52, c = i % 52;
        Wc[k][c] = (c < 50) ? Wpa[k * 50 + c] : 0.f;
    }
    if (t < 52) bc[t] = (t < 50) ? bpa[t] : 0.f;
    __syncthreads();
    const int p = blockIdx.x * 256 + t;
    float acc[52];
    #pragma unroll
    for (int c = 0; c < 52; ++c) acc[c] = bc[c];
    const float4* pf4 = (const float4*)(PF + (size_t)p * 64);
    #pragma unroll 2
    for (int k4 = 0; k4 < 16; ++k4) {
        float4 xv = pf4[k4];
        float xs[4] = {xv.x, xv.y, xv.z, xv.w};
        #pragma unroll
        for (int kk = 0; kk < 4; ++kk) {
            const float4* wr = (const float4*)&Wc[k4*4 + kk][0];
            float x = xs[kk];
            #pragma unroll
            for (int c4 = 0; c4 < 13; ++c4) {
                float4 w = wr[c4];
                acc[c4*4+0] = fmaf(x, w.x, acc[c4*4+0]);
                acc[c4*4+1] = fmaf(x, w.y, acc[c4*4+1]);
                acc[c4*4+2] = fmaf(x, w.z, acc[c4*4+2]);
                acc[c4*4+3] = fmaf(x, w.w, acc[c4*4+3]);
            }
        }
    }
    float4* op = (float4*)(PAo + (size_t)p * 52);
    #pragma unroll
    for (int q = 0; q < 13; ++q) {
        op[q] = make_float4(fmaxf(acc[4*q+0], 0.f), fmaxf(acc[4*q+1], 0.f),
                            fmaxf(acc[4*q+2], 0.f), fmaxf(acc[4*q+3], 0.f));
    }
}

// ---------------- K_seg: PAseg[a] = sum of PA rows in bucket a (wave per atom)
__global__ __launch_bounds__(256) void k_seg(
    const float* __restrict__ PAo, const int* __restrict__ idx,
    const int* __restrict__ ofs, float* __restrict__ PAseg)
{
    const int t = threadIdx.x;
    const int a = blockIdx.x * 4 + (t >> 6);
    const int lane = t & 63;
    const int beg = ofs[a], end = ofs[a + 1];
    const int cn = end - beg;
    int pre = (lane < cn) ? idx[beg + lane] : 0;
    float s = 0.f;
    for (int j = 0; j < cn; ++j) {
        int p = (j < 64) ? __shfl(pre, j, 64) : idx[beg + j];
        if (lane < 50) s += PAo[(size_t)p * 52 + lane];
    }
    if (lane < 50) PAseg[(size_t)a * 50 + lane] = s;
}

// ---------------- K2b: ap/pp in regs, two-pass 32-col output GEMM -> f32
__global__ __launch_bounds__(256, 2) void k2b_pair_out(
    const int* __restrict__ a2p,
    const float* __restrict__ U, const float* __restrict__ V,
    const float* __restrict__ bap_g,
    const float* __restrict__ PF,
    const float* __restrict__ Wpp, const float* __restrict__ bpp_g,
    const float* __restrict__ Wpo, const float* __restrict__ bpo,
    float* __restrict__ Pout)
{
    __shared__ __align__(16) float Wo[100][64];   // 25.6 KB  (rows: 0..49 AP, 50..99 PP)
    __shared__ __align__(16) float Wp[64][52];    // 13.3 KB
    __shared__ __align__(16) float bap[52];
    __shared__ __align__(16) float bpp[52];
    __shared__ float bo[64];
    const int t = threadIdx.x;
    for (int i = t; i < 6400; i += 256) Wo[i >> 6][i & 63] = Wpo[i];
    for (int i = t; i < 64 * 52; i += 256) {
        int k = i / 52, c = i % 52;
        Wp[k][c] = (c < 50) ? Wpp[k * 50 + c] : 0.f;
    }
    if (t < 52) bap[t] = (t < 50) ? bap_g[t] : 0.f;
    if (t < 52) bpp[t] = (t < 50) ? bpp_g[t] : 0.f;
    if (t < 64) bo[t] = bpo[t];
    __syncthreads();
    const int p = blockIdx.x * 256 + t;

    // ---- Phase 1a: pp = relu(pf @ Wpp + b)   (52 regs, static idx)
    float pp[52];
    #pragma unroll
    for (int c = 0; c < 52; ++c) pp[c] = bpp[c];
    {
        const float4* pf4 = (const float4*)(PF + (size_t)p * 64);
        #pragma unroll 2
        for (int k4 = 0; k4 < 16; ++k4) {
            float4 xv = pf4[k4];
            float xs[4] = {xv.x, xv.y, xv.z, xv.w};
            #pragma unroll
            for (int kk = 0; kk < 4; ++kk) {
                const float4* wr = (const float4*)&Wp[k4*4 + kk][0];
                float x = xs[kk];
                #pragma unroll
                for (int c4 = 0; c4 < 13; ++c4) {
                    float4 w = wr[c4];
                    pp[c4*4+0] = fmaf(x, w.x, pp[c4*4+0]);
                    pp[c4*4+1] = fmaf(x, w.y, pp[c4*4+1]);
                    pp[c4*4+2] = fmaf(x, w.z, pp[c4*4+2]);
                    pp[c4*4+3] = fmaf(x, w.w, pp[c4*4+3]);
                }
            }
        }
        #pragma unroll
        for (int c = 0; c < 52; ++c) pp[c] = fmaxf(pp[c], 0.f);
    }

    // ---- Phase 1b: ap = relu(U_i+V_j+b) + relu(U_j+V_i+b)   (52 regs)
    float ap[52];
    {
        const int2 ij = ((const int2*)a2p)[p];
        const float4* Ui = (const float4*)(U + (size_t)ij.x * 52);
        const float4* Vi = (const float4*)(V + (size_t)ij.x * 52);
        const float4* Uj = (const float4*)(U + (size_t)ij.y * 52);
        const float4* Vj = (const float4*)(V + (size_t)ij.y * 52);
        #pragma unroll
        for (int c4 = 0; c4 < 13; ++c4) {
            float4 ui = Ui[c4], vj = Vj[c4], uj = Uj[c4], vi = Vi[c4];
            const float4 bb = *(const float4*)&bap[c4*4];
            ap[c4*4+0] = fmaxf(ui.x + vj.x + bb.x, 0.f) + fmaxf(uj.x + vi.x + bb.x, 0.f);
            ap[c4*4+1] = fmaxf(ui.y + vj.y + bb.y, 0.f) + fmaxf(uj.y + vi.y + bb.y, 0.f);
            ap[c4*4+2] = fmaxf(ui.z + vj.z + bb.z, 0.f) + fmaxf(uj.z + vi.z + bb.z, 0.f);
            ap[c4*4+3] = fmaxf(ui.w + vj.w + bb.w, 0.f) + fmaxf(uj.w + vi.w + bb.w, 0.f);
        }
    }

    // ---- Phase 2: two passes of 32 output cols; only o[32] live
    float4* outp = (float4*)(Pout + (size_t)p * 64);
    #pragma unroll 1
    for (int h = 0; h < 2; ++h) {
        float o[32];
        #pragma unroll
        for (int c = 0; c < 32; ++c) o[c] = bo[h*32 + c];
        #pragma unroll 2
        for (int k = 0; k < 50; ++k) {
            float a = ap[k];
            const float4* wr = (const float4*)&Wo[k][h*32];
            #pragma unroll
            for (int c4 = 0; c4 < 8; ++c4) {
                float4 w = wr[c4];
                o[c4*4+0] = fmaf(a, w.x, o[c4*4+0]);
                o[c4*4+1] = fmaf(a, w.y, o[c4*4+1]);
                o[c4*4+2] = fmaf(a, w.z, o[c4*4+2]);
                o[c4*4+3] = fmaf(a, w.w, o[c4*4+3]);
            }
        }
        #pragma unroll 2
        for (int k = 0; k < 50; ++k) {
            float a = pp[k];
            const float4* wr = (const float4*)&Wo[50 + k][h*32];
            #pragma unroll
            for (int c4 = 0; c4 < 8; ++c4) {
                float4 w = wr[c4];
                o[c4*4+0] = fmaf(a, w.x, o[c4*4+0]);
                o[c4*4+1] = fmaf(a, w.y, o[c4*4+1]);
                o[c4*4+2] = fmaf(a, w.z, o[c4*4+2]);
                o[c4*4+3] = fmaf(a, w.w, o[c4*4+3]);
            }
        }
        #pragma unroll
        for (int q = 0; q < 8; ++q) {
            outp[h*8 + q] = make_float4(fmaxf(o[4*q+0], 0.f), fmaxf(o[4*q+1], 0.f),
                                        fmaxf(o[4*q+2], 0.f), fmaxf(o[4*q+3], 0.f));
        }
    }
}

// ---------------- K3: assign = softmax(relu([AA,PAseg]@Wao+b))
__global__ __launch_bounds__(256, 2) void k3_assign(
    const float* __restrict__ AA, const float* __restrict__ PAseg,
    const float* __restrict__ Wao, const float* __restrict__ bao,
    float* __restrict__ S)
{
    __shared__ __align__(16) float featT[150][16];
    __shared__ __align__(16) float L[16][128];
    const int t = threadIdx.x;
    const int a0 = blockIdx.x * 16;
    for (int idx = t; idx < 2400; idx += 256) {
        int a = idx / 150, k = idx % 150;
        featT[k][a] = (k < 100) ? AA[(size_t)(a0 + a) * 100 + k]
                                : PAseg[(size_t)(a0 + a) * 50 + (k - 100)];
    }
    __syncthreads();
    const int c = t & 127, g = t >> 7;
    float acc[8];
    float b = bao[c];
    #pragma unroll
    for (int a = 0; a < 8; ++a) acc[a] = b;
    #pragma unroll 2
    for (int k = 0; k < 150; ++k) {
        float w = Wao[(size_t)k * 128 + c];
        const float4* fr = (const float4*)&featT[k][g * 8];
        float4 f0 = fr[0], f1 = fr[1];
        acc[0] = fmaf(f0.x, w, acc[0]); acc[1] = fmaf(f0.y, w, acc[1]);
        acc[2] = fmaf(f0.z, w, acc[2]); acc[3] = fmaf(f0.w, w, acc[3]);
        acc[4] = fmaf(f1.x, w, acc[4]); acc[5] = fmaf(f1.y, w, acc[5]);
        acc[6] = fmaf(f1.z, w, acc[6]); acc[7] = fmaf(f1.w, w, acc[7]);
    }
    #pragma unroll
    for (int a = 0; a < 8; ++a) L[g*8 + a][c] = fmaxf(acc[a], 0.f);
    __syncthreads();
    const int r = t & 15, a = t >> 4;   // 16 threads per atom
    float v[8];
    #pragma unroll
    for (int q = 0; q < 8; ++q) v[q] = L[a][r + 16*q];
    float m = v[0];
    #pragma unroll
    for (int q = 1; q < 8; ++q) m = fmaxf(m, v[q]);
    #pragma unroll
    for (int w = 1; w < 16; w <<= 1) m = fmaxf(m, __shfl_xor(m, w, 64));
    float e[8];
    float s = 0.f;
    #pragma unroll
    for (int q = 0; q < 8; ++q) { e[q] = __expf(v[q] - m); s += e[q]; }
    #pragma unroll
    for (int w = 1; w < 16; w <<= 1) s += __shfl_xor(s, w, 64);
    float inv = 1.f / s;
    #pragma unroll
    for (int q = 0; q < 8; ++q)
        S[(size_t)(a0 + a) * 128 + r + 16*q] = e[q] * inv;
}

// ---------------- K4: pooled[b] = S^T X per molecule (d-half per block) -> f32
__global__ __launch_bounds__(256, 2) void k4_pool(
    const float* __restrict__ X, const float* __restrict__ S,
    float* __restrict__ pooled)
{
    __shared__ __align__(16) float Sl[64][128];
    __shared__ __align__(16) float Xl[64][128];
    const int t = threadIdx.x;
    const int b = blockIdx.x >> 1;
    const int dhalf = (blockIdx.x & 1) * 128;
    for (int idx = t; idx < 8192; idx += 256) {
        int n = idx >> 7, cd = idx & 127;
        Sl[n][cd] = S[(size_t)(b*64 + n) * 128 + cd];
        Xl[n][cd] = X[(size_t)(b*64 + n) * 256 + dhalf + cd];
    }
    __syncthreads();
    const int c = t & 127, dq = t >> 7;
    float4 f[16];
    #pragma unroll
    for (int q = 0; q < 16; ++q) f[q] = make_float4(0.f, 0.f, 0.f, 0.f);
    #pragma unroll 2
    for (int n = 0; n < 64; ++n) {
        float s = Sl[n][c];
        const float4* xr = (const float4*)&Xl[n][dq * 64];
        #pragma unroll
        for (int q = 0; q < 16; ++q) {
            float4 x = xr[q];
            f[q].x = fmaf(s, x.x, f[q].x);
            f[q].y = fmaf(s, x.y, f[q].y);
            f[q].z = fmaf(s, x.z, f[q].z);
            f[q].w = fmaf(s, x.w, f[q].w);
        }
    }
    size_t base = (size_t)b * 32768 + (size_t)c * 256 + dhalf + dq * 64;
    float4* op = (float4*)(pooled + base);
    #pragma unroll
    for (int q = 0; q < 16; ++q) op[q] = f[q];
}

extern "C" void kernel_launch(void* const* d_in, const int* in_sizes, int n_in,
                              void* d_out, int out_size, void* d_ws, size_t ws_size,
                              hipStream_t stream)
{
    const float* atom = (const float*)d_in[0];
    const float* pair = (const float*)d_in[1];
    const int*   split = (const int*)d_in[2];
    const int*   a2p  = (const int*)d_in[3];
    const float* Waa = (const float*)d_in[5];
    const float* baa = (const float*)d_in[6];
    const float* Wpa = (const float*)d_in[7];
    const float* bpa = (const float*)d_in[8];
    const float* Wao = (const float*)d_in[9];
    const float* bao = (const float*)d_in[10];
    const float* Wap = (const float*)d_in[11];
    const float* bap = (const float*)d_in[12];
    const float* Wpp = (const float*)d_in[13];
    const float* bpp = (const float*)d_in[14];
    const float* Wpo = (const float*)d_in[15];
    const float* bpo = (const float*)d_in[16];

    float* ws = (float*)d_ws;
    float* PAo   = ws + OFF_PA;
    float* PAseg = ws + OFF_PASEG;
    float* AA = ws + OFF_AA;
    float* U  = ws + OFF_U;
    float* V  = ws + OFF_V;
    float* Sm = ws + OFF_S;
    int* idx = (int*)(ws + OFF_IDX);
    int* ofs = (int*)(ws + OFF_OFS);
    int* cnt = (int*)(ws + OFF_CNT);

    float* pooled = (float*)d_out;
    float* Pout = pooled + (size_t)256 * 128 * 256;

    hipMemsetAsync(cnt, 0, N_ATOMS * sizeof(int), stream);
    k0_count<<<512, 256, 0, stream>>>(split, cnt);
    k_scan<<<1, 1024, 0, stream>>>(cnt, ofs);
    k0_fill<<<512, 256, 0, stream>>>(split, cnt, idx);
    k1_atom<<<512, 256, 0, stream>>>(atom, Waa, baa, Wap, AA, U, V);
    k2a_pa<<<512, 256, 0, stream>>>(pair, Wpa, bpa, PAo);
    k_seg<<<4096, 256, 0, stream>>>(PAo, idx, ofs, PAseg);
    k2b_pair_out<<<512, 256, 0, stream>>>(a2p, U, V, bap, pair, Wpp, bpp, Wpo, bpo, Pout);
    k3_assign<<<1024, 256, 0, stream>>>(AA, PAseg, Wao, bao, Sm);
    k4_pool<<<512, 256, 0, stream>>>(atom, Sm, pooled);
}

// Round 5
// 389.147 us; speedup vs baseline: 1.1743x; 1.1743x over previous
//
#include <hip/hip_runtime.h>
#include <hip/hip_bf16.h>

#define N_ATOMS 16384
#define N_PAIRS 131072

// ws layout (float offsets)
#define OFF_PA    0                       // [P,52] relu(PA), pad cols zeroed
#define OFF_PASEG 6815744                 // [N,50]
#define OFF_AA    7634944                 // [N,100]
#define OFF_U     9273344                 // [N,52]
#define OFF_V     10125312                // [N,52]
#define OFF_S     10977280                // [N,128]
#define OFF_IDX   13074432                // int[P]
#define OFF_OFS   13205504                // int[N+2]
#define OFF_CNT   13221890                // int[N]  (count -> cursor)
// total ~13.24M floats = 53 MB

// ---------------- K0a: histogram of pair_split
__global__ __launch_bounds__(256) void k0_count(const int* __restrict__ split,
                                                int* __restrict__ cnt)
{
    int p = blockIdx.x * 256 + threadIdx.x;
    atomicAdd(&cnt[split[p]], 1);
}

// ---------------- K0b: exclusive prefix sum over 16384 counts (1 block)
__global__ __launch_bounds__(1024) void k_scan(int* __restrict__ cnt,
                                               int* __restrict__ ofs)
{
    __shared__ int part[1024];
    const int t = threadIdx.x;
    const int base = t * 16;
    int v[16];
    int s = 0;
    #pragma unroll
    for (int i = 0; i < 16; ++i) { v[i] = cnt[base + i]; s += v[i]; }
    part[t] = s;
    __syncthreads();
    for (int off = 1; off < 1024; off <<= 1) {
        int x = (t >= off) ? part[t - off] : 0;
        __syncthreads();
        part[t] += x;
        __syncthreads();
    }
    int excl = part[t] - s;   // exclusive prefix of this thread's chunk
    #pragma unroll
    for (int i = 0; i < 16; ++i) {
        int c = v[i];
        ofs[base + i] = excl;
        cnt[base + i] = excl;   // becomes the fill cursor
        excl += c;
    }
    if (t == 1023) ofs[16384] = excl;
}

// ---------------- K0c: scatter pair ids into buckets
__global__ __launch_bounds__(256) void k0_fill(const int* __restrict__ split,
                                               int* __restrict__ cur,
                                               int* __restrict__ idx)
{
    int p = blockIdx.x * 256 + threadIdx.x;
    int pos = atomicAdd(&cur[split[p]], 1);
    idx[pos] = p;
}

// ---------------- K1: AA = relu(X@Waa+b), U = X@Wap[:256], V = X@Wap[256:]
__global__ __launch_bounds__(256, 2) void k1_atom(
    const float* __restrict__ X,
    const float* __restrict__ Waa, const float* __restrict__ baa,
    const float* __restrict__ Wap,
    float* __restrict__ AA, float* __restrict__ U, float* __restrict__ V)
{
    __shared__ __align__(16) float xt[256][36];   // transposed X tile, pad 36
    const int t = threadIdx.x;
    const int a0 = blockIdx.x * 32;
    #pragma unroll
    for (int r = 0; r < 32; ++r) {                // a = r, k = t : coalesced
        xt[t][r] = X[(size_t)(a0 + r) * 256 + t];
    }
    __syncthreads();
    const int c = t;
    if (c < 200) {
        const float* wp; int stride; float bias = 0.f;
        if (c < 100)      { wp = Waa + c;                  stride = 100; bias = baa[c]; }
        else if (c < 150) { wp = Wap + (c - 100);          stride = 50; }
        else              { wp = Wap + 256*50 + (c - 150); stride = 50; }
        float acc[32];
        #pragma unroll
        for (int a = 0; a < 32; ++a) acc[a] = bias;
        #pragma unroll 4
        for (int k = 0; k < 256; ++k) {
            float w = wp[(size_t)k * stride];
            const float4* xr = (const float4*)&xt[k][0];
            #pragma unroll
            for (int a4 = 0; a4 < 8; ++a4) {
                float4 x = xr[a4];
                acc[a4*4+0] = fmaf(x.x, w, acc[a4*4+0]);
                acc[a4*4+1] = fmaf(x.y, w, acc[a4*4+1]);
                acc[a4*4+2] = fmaf(x.z, w, acc[a4*4+2]);
                acc[a4*4+3] = fmaf(x.w, w, acc[a4*4+3]);
            }
        }
        if (c < 100) {
            #pragma unroll
            for (int a = 0; a < 32; ++a)
                AA[(size_t)(a0 + a) * 100 + c] = fmaxf(acc[a], 0.f);
        } else if (c < 150) {
            #pragma unroll
            for (int a = 0; a < 32; ++a)
                U[(size_t)(a0 + a) * 52 + (c - 100)] = acc[a];
        } else {
            #pragma unroll
            for (int a = 0; a < 32; ++a)
                V[(size_t)(a0 + a) * 52 + (c - 150)] = acc[a];
        }
    } else if (c == 200) {        // zero U pad cols 50,51
        #pragma unroll
        for (int a = 0; a < 32; ++a) {
            U[(size_t)(a0 + a) * 52 + 50] = 0.f;
            U[(size_t)(a0 + a) * 52 + 51] = 0.f;
        }
    } else if (c == 201) {        // zero V pad cols 50,51
        #pragma unroll
        for (int a = 0; a < 32; ++a) {
            V[(size_t)(a0 + a) * 52 + 50] = 0.f;
            V[(size_t)(a0 + a) * 52 + 51] = 0.f;
        }
    }
}

// ---------------- K2a: PA = relu(pf@Wpa+b) -> rows [P,52], no atomics
__global__ __launch_bounds__(256, 2) void k2a_pa(
    const float* __restrict__ PF,
    const float* __restrict__ Wpa, const float* __restrict__ bpa,
    float* __restrict__ PAo)
{
    __shared__ __align__(16) float Wc[64][52];
    __shared__ __align__(16) float bc[52];
    const int t = threadIdx.x;
    for (int i = t; i < 64 * 52; i += 256) {
        int k = i / 52, c = i % 52;
        Wc[k][c] = (c < 50) ? Wpa[k * 50 + c] : 0.f;
    }
    if (t < 52) bc[t] = (t < 50) ? bpa[t] : 0.f;
    __syncthreads();
    const int p = blockIdx.x * 256 + t;
    float acc[52];
    #pragma unroll
    for (int c = 0; c < 52; ++c) acc[c] = bc[c];
    const float4* pf4 = (const float4*)(PF + (size_t)p * 64);
    #pragma unroll 2
    for (int k4 = 0; k4 < 16; ++k4) {
        float4 xv = pf4[k4];
        float xs[4] = {xv.x, xv.y, xv.z, xv.w};
        #pragma unroll
        for (int kk = 0; kk < 4; ++kk) {
            const float4* wr = (const float4*)&Wc[k4*4 + kk][0];
            float x = xs[kk];
            #pragma unroll
            for (int c4 = 0; c4 < 13; ++c4) {
                float4 w = wr[c4];
                acc[c4*4+0] = fmaf(x, w.x, acc[c4*4+0]);
                acc[c4*4+1] = fmaf(x, w.y, acc[c4*4+1]);
                acc[c4*4+2] = fmaf(x, w.z, acc[c4*4+2]);
                acc[c4*4+3] = fmaf(x, w.w, acc[c4*4+3]);
            }
        }
    }
    float4* op = (float4*)(PAo + (size_t)p * 52);
    #pragma unroll
    for (int q = 0; q < 13; ++q) {
        op[q] = make_float4(fmaxf(acc[4*q+0], 0.f), fmaxf(acc[4*q+1], 0.f),
                            fmaxf(acc[4*q+2], 0.f), fmaxf(acc[4*q+3], 0.f));
    }
}

// ---------------- K_seg: PAseg[a] = sum of PA rows in bucket a (wave per atom)
__global__ __launch_bounds__(256) void k_seg(
    const float* __restrict__ PAo, const int* __restrict__ idx,
    const int* __restrict__ ofs, float* __restrict__ PAseg)
{
    const int t = threadIdx.x;
    const int a = blockIdx.x * 4 + (t >> 6);
    const int lane = t & 63;
    const int beg = ofs[a], end = ofs[a + 1];
    const int cn = end - beg;
    int pre = (lane < cn) ? idx[beg + lane] : 0;
    float s = 0.f;
    for (int j = 0; j < cn; ++j) {
        int p = (j < 64) ? __shfl(pre, j, 64) : idx[beg + j];
        if (lane < 50) s += PAo[(size_t)p * 52 + lane];
    }
    if (lane < 50) PAseg[(size_t)a * 50 + lane] = s;
}

// ---------------- K2b: ap/pp in regs (ALL static idx), two-pass out GEMM -> f32
__global__ __launch_bounds__(256, 2) void k2b_pair_out(
    const int* __restrict__ a2p,
    const float* __restrict__ U, const float* __restrict__ V,
    const float* __restrict__ bap_g,
    const float* __restrict__ PF,
    const float* __restrict__ Wpp, const float* __restrict__ bpp_g,
    const float* __restrict__ Wpo, const float* __restrict__ bpo,
    float* __restrict__ Pout)
{
    __shared__ __align__(16) float Wo[100][64];   // 25.6 KB  (rows: 0..49 AP, 50..99 PP)
    __shared__ __align__(16) float Wp[64][52];    // 13.3 KB
    __shared__ __align__(16) float bap[52];
    __shared__ __align__(16) float bpp[52];
    __shared__ float bo[64];
    const int t = threadIdx.x;
    for (int i = t; i < 6400; i += 256) Wo[i >> 6][i & 63] = Wpo[i];
    for (int i = t; i < 64 * 52; i += 256) {
        int k = i / 52, c = i % 52;
        Wp[k][c] = (c < 50) ? Wpp[k * 50 + c] : 0.f;
    }
    if (t < 52) bap[t] = (t < 50) ? bap_g[t] : 0.f;
    if (t < 52) bpp[t] = (t < 50) ? bpp_g[t] : 0.f;
    if (t < 64) bo[t] = bpo[t];
    __syncthreads();
    const int p = blockIdx.x * 256 + t;

    // ---- Phase 1a: pp = relu(pf @ Wpp + b)   (52 regs, static idx)
    float pp[52];
    #pragma unroll
    for (int c = 0; c < 52; ++c) pp[c] = bpp[c];
    {
        const float4* pf4 = (const float4*)(PF + (size_t)p * 64);
        #pragma unroll 2
        for (int k4 = 0; k4 < 16; ++k4) {
            float4 xv = pf4[k4];
            float xs[4] = {xv.x, xv.y, xv.z, xv.w};
            #pragma unroll
            for (int kk = 0; kk < 4; ++kk) {
                const float4* wr = (const float4*)&Wp[k4*4 + kk][0];
                float x = xs[kk];
                #pragma unroll
                for (int c4 = 0; c4 < 13; ++c4) {
                    float4 w = wr[c4];
                    pp[c4*4+0] = fmaf(x, w.x, pp[c4*4+0]);
                    pp[c4*4+1] = fmaf(x, w.y, pp[c4*4+1]);
                    pp[c4*4+2] = fmaf(x, w.z, pp[c4*4+2]);
                    pp[c4*4+3] = fmaf(x, w.w, pp[c4*4+3]);
                }
            }
        }
        #pragma unroll
        for (int c = 0; c < 52; ++c) pp[c] = fmaxf(pp[c], 0.f);
    }

    // ---- Phase 1b: ap = relu(U_i+V_j+b) + relu(U_j+V_i+b)   (52 regs, static idx)
    float ap[52];
    {
        const int2 ij = ((const int2*)a2p)[p];
        const float4* Ui = (const float4*)(U + (size_t)ij.x * 52);
        const float4* Vi = (const float4*)(V + (size_t)ij.x * 52);
        const float4* Uj = (const float4*)(U + (size_t)ij.y * 52);
        const float4* Vj = (const float4*)(V + (size_t)ij.y * 52);
        #pragma unroll
        for (int c4 = 0; c4 < 13; ++c4) {
            float4 ui = Ui[c4], vj = Vj[c4], uj = Uj[c4], vi = Vi[c4];
            const float4 bb = *(const float4*)&bap[c4*4];
            ap[c4*4+0] = fmaxf(ui.x + vj.x + bb.x, 0.f) + fmaxf(uj.x + vi.x + bb.x, 0.f);
            ap[c4*4+1] = fmaxf(ui.y + vj.y + bb.y, 0.f) + fmaxf(uj.y + vi.y + bb.y, 0.f);
            ap[c4*4+2] = fmaxf(ui.z + vj.z + bb.z, 0.f) + fmaxf(uj.z + vi.z + bb.z, 0.f);
            ap[c4*4+3] = fmaxf(ui.w + vj.w + bb.w, 0.f) + fmaxf(uj.w + vi.w + bb.w, 0.f);
        }
    }

    // ---- Phase 2: two passes of 32 output cols; k loops FULLY unrolled so
    //      ap[k]/pp[k] indices are compile-time (rule #20: no scratch)
    float4* outp = (float4*)(Pout + (size_t)p * 64);
    #pragma unroll 1
    for (int h = 0; h < 2; ++h) {
        float o[32];
        #pragma unroll
        for (int c = 0; c < 32; ++c) o[c] = bo[h*32 + c];
        #pragma unroll
        for (int k = 0; k < 50; ++k) {
            float a = ap[k];
            const float4* wr = (const float4*)&Wo[k][h*32];
            #pragma unroll
            for (int c4 = 0; c4 < 8; ++c4) {
                float4 w = wr[c4];
                o[c4*4+0] = fmaf(a, w.x, o[c4*4+0]);
                o[c4*4+1] = fmaf(a, w.y, o[c4*4+1]);
                o[c4*4+2] = fmaf(a, w.z, o[c4*4+2]);
                o[c4*4+3] = fmaf(a, w.w, o[c4*4+3]);
            }
        }
        #pragma unroll
        for (int k = 0; k < 50; ++k) {
            float a = pp[k];
            const float4* wr = (const float4*)&Wo[50 + k][h*32];
            #pragma unroll
            for (int c4 = 0; c4 < 8; ++c4) {
                float4 w = wr[c4];
                o[c4*4+0] = fmaf(a, w.x, o[c4*4+0]);
                o[c4*4+1] = fmaf(a, w.y, o[c4*4+1]);
                o[c4*4+2] = fmaf(a, w.z, o[c4*4+2]);
                o[c4*4+3] = fmaf(a, w.w, o[c4*4+3]);
            }
        }
        #pragma unroll
        for (int q = 0; q < 8; ++q) {
            outp[h*8 + q] = make_float4(fmaxf(o[4*q+0], 0.f), fmaxf(o[4*q+1], 0.f),
                                        fmaxf(o[4*q+2], 0.f), fmaxf(o[4*q+3], 0.f));
        }
    }
}

// ---------------- K3: assign = softmax(relu([AA,PAseg]@Wao+b))
__global__ __launch_bounds__(256, 2) void k3_assign(
    const float* __restrict__ AA, const float* __restrict__ PAseg,
    const float* __restrict__ Wao, const float* __restrict__ bao,
    float* __restrict__ S)
{
    __shared__ __align__(16) float featT[150][16];
    __shared__ __align__(16) float L[16][128];
    const int t = threadIdx.x;
    const int a0 = blockIdx.x * 16;
    for (int idx = t; idx < 2400; idx += 256) {
        int a = idx / 150, k = idx % 150;
        featT[k][a] = (k < 100) ? AA[(size_t)(a0 + a) * 100 + k]
                                : PAseg[(size_t)(a0 + a) * 50 + (k - 100)];
    }
    __syncthreads();
    const int c = t & 127, g = t >> 7;
    float acc[8];
    float b = bao[c];
    #pragma unroll
    for (int a = 0; a < 8; ++a) acc[a] = b;
    #pragma unroll 2
    for (int k = 0; k < 150; ++k) {
        float w = Wao[(size_t)k * 128 + c];
        const float4* fr = (const float4*)&featT[k][g * 8];
        float4 f0 = fr[0], f1 = fr[1];
        acc[0] = fmaf(f0.x, w, acc[0]); acc[1] = fmaf(f0.y, w, acc[1]);
        acc[2] = fmaf(f0.z, w, acc[2]); acc[3] = fmaf(f0.w, w, acc[3]);
        acc[4] = fmaf(f1.x, w, acc[4]); acc[5] = fmaf(f1.y, w, acc[5]);
        acc[6] = fmaf(f1.z, w, acc[6]); acc[7] = fmaf(f1.w, w, acc[7]);
    }
    #pragma unroll
    for (int a = 0; a < 8; ++a) L[g*8 + a][c] = fmaxf(acc[a], 0.f);
    __syncthreads();
    const int r = t & 15, a = t >> 4;   // 16 threads per atom
    float v[8];
    #pragma unroll
    for (int q = 0; q < 8; ++q) v[q] = L[a][r + 16*q];
    float m = v[0];
    #pragma unroll
    for (int q = 1; q < 8; ++q) m = fmaxf(m, v[q]);
    #pragma unroll
    for (int w = 1; w < 16; w <<= 1) m = fmaxf(m, __shfl_xor(m, w, 64));
    float e[8];
    float s = 0.f;
    #pragma unroll
    for (int q = 0; q < 8; ++q) { e[q] = __expf(v[q] - m); s += e[q]; }
    #pragma unroll
    for (int w = 1; w < 16; w <<= 1) s += __shfl_xor(s, w, 64);
    float inv = 1.f / s;
    #pragma unroll
    for (int q = 0; q < 8; ++q)
        S[(size_t)(a0 + a) * 128 + r + 16*q] = e[q] * inv;
}

// ---------------- K4: pooled[b] = S^T X per molecule (d-half per block) -> f32
__global__ __launch_bounds__(256, 2) void k4_pool(
    const float* __restrict__ X, const float* __restrict__ S,
    float* __restrict__ pooled)
{
    __shared__ __align__(16) float Sl[64][128];
    __shared__ __align__(16) float Xl[64][128];
    const int t = threadIdx.x;
    const int b = blockIdx.x >> 1;
    const int dhalf = (blockIdx.x & 1) * 128;
    for (int idx = t; idx < 8192; idx += 256) {
        int n = idx >> 7, cd = idx & 127;
        Sl[n][cd] = S[(size_t)(b*64 + n) * 128 + cd];
        Xl[n][cd] = X[(size_t)(b*64 + n) * 256 + dhalf + cd];
    }
    __syncthreads();
    const int c = t & 127, dq = t >> 7;
    float4 f[16];
    #pragma unroll
    for (int q = 0; q < 16; ++q) f[q] = make_float4(0.f, 0.f, 0.f, 0.f);
    #pragma unroll 2
    for (int n = 0; n < 64; ++n) {
        float s = Sl[n][c];
        const float4* xr = (const float4*)&Xl[n][dq * 64];
        #pragma unroll
        for (int q = 0; q < 16; ++q) {
            float4 x = xr[q];
            f[q].x = fmaf(s, x.x, f[q].x);
            f[q].y = fmaf(s, x.y, f[q].y);
            f[q].z = fmaf(s, x.z, f[q].z);
            f[q].w = fmaf(s, x.w, f[q].w);
        }
    }
    size_t base = (size_t)b * 32768 + (size_t)c * 256 + dhalf + dq * 64;
    float4* op = (float4*)(pooled + base);
    #pragma unroll
    for (int q = 0; q < 16; ++q) op[q] = f[q];
}

extern "C" void kernel_launch(void* const* d_in, const int* in_sizes, int n_in,
                              void* d_out, int out_size, void* d_ws, size_t ws_size,
                              hipStream_t stream)
{
    const float* atom = (const float*)d_in[0];
    const float* pair = (const float*)d_in[1];
    const int*   split = (const int*)d_in[2];
    const int*   a2p  = (const int*)d_in[3];
    const float* Waa = (const float*)d_in[5];
    const float* baa = (const float*)d_in[6];
    const float* Wpa = (const float*)d_in[7];
    const float* bpa = (const float*)d_in[8];
    const float* Wao = (const float*)d_in[9];
    const float* bao = (const float*)d_in[10];
    const float* Wap = (const float*)d_in[11];
    const float* bap = (const float*)d_in[12];
    const float* Wpp = (const float*)d_in[13];
    const float* bpp = (const float*)d_in[14];
    const float* Wpo = (const float*)d_in[15];
    const float* bpo = (const float*)d_in[16];

    float* ws = (float*)d_ws;
    float* PAo   = ws + OFF_PA;
    float* PAseg = ws + OFF_PASEG;
    float* AA = ws + OFF_AA;
    float* U  = ws + OFF_U;
    float* V  = ws + OFF_V;
    float* Sm = ws + OFF_S;
    int* idx = (int*)(ws + OFF_IDX);
    int* ofs = (int*)(ws + OFF_OFS);
    int* cnt = (int*)(ws + OFF_CNT);

    float* pooled = (float*)d_out;
    float* Pout = pooled + (size_t)256 * 128 * 256;

    hipMemsetAsync(cnt, 0, N_ATOMS * sizeof(int), stream);
    k0_count<<<512, 256, 0, stream>>>(split, cnt);
    k_scan<<<1, 1024, 0, stream>>>(cnt, ofs);
    k0_fill<<<512, 256, 0, stream>>>(split, cnt, idx);
    k1_atom<<<512, 256, 0, stream>>>(atom, Waa, baa, Wap, AA, U, V);
    k2a_pa<<<512, 256, 0, stream>>>(pair, Wpa, bpa, PAo);
    k_seg<<<4096, 256, 0, stream>>>(PAo, idx, ofs, PAseg);
    k2b_pair_out<<<512, 256, 0, stream>>>(a2p, U, V, bap, pair, Wpp, bpp, Wpo, bpo, Pout);
    k3_assign<<<1024, 256, 0, stream>>>(AA, PAseg, Wao, bao, Sm);
    k4_pool<<<512, 256, 0, stream>>>(atom, Sm, pooled);
}